// Round 5
// baseline (1984.424 us; speedup 1.0000x reference)
//
#include <hip/hip_runtime.h>
#include <hip/hip_bf16.h>

// Workspace layout (4B units):
// [deg:N][cursor:N][csr:int2 x E][bsum:4096][A:N*32][B:N*32][h:N*32][gbuf:G*32]
// h holds non-negative float bit patterns (global atomicMax on uint); layer2
// reuses h (re-zeroed mid-stream after pre2 consumes layer1's h).

#define NEG_BIG (-3.0e38f)

__global__ __launch_bounds__(256) void pre1_kernel(
    const float* __restrict__ pos, const float* __restrict__ w1a,
    const float* __restrict__ b1a, float* __restrict__ A, float* __restrict__ B, int N)
{
    int t = blockIdx.x * 256 + threadIdx.x;
    if (t >= N * 32) return;
    int n = t >> 5, c = t & 31;
    float px = pos[2 * n], py = pos[2 * n + 1];
    float w0 = w1a[c], w1 = w1a[32 + c], w2 = w1a[64 + c], w3 = w1a[96 + c];
    A[t] = fmaf(px, w0 + w2, fmaf(py, w1 + w3, b1a[c]));
    B[t] = -(px * w2 + py * w3);
}

__global__ __launch_bounds__(256) void pre2_kernel(
    const float* __restrict__ pos, const float* __restrict__ h1,
    const float* __restrict__ w2a, const float* __restrict__ b2a,
    float* __restrict__ A, float* __restrict__ B, int N)
{
    int t = blockIdx.x * 256 + threadIdx.x;
    if (t >= N * 32) return;
    int n = t >> 5, c = t & 31;
    float px = pos[2 * n], py = pos[2 * n + 1];
    float wx = w2a[32 * 32 + c], wy = w2a[33 * 32 + c];
    float s = fmaf(px, wx, fmaf(py, wy, b2a[c]));
    const float* hrow = h1 + (size_t)n * 32;
#pragma unroll
    for (int k = 0; k < 32; ++k) s = fmaf(hrow[k], w2a[k * 32 + c], s);
    A[t] = s;
    B[t] = -(px * wx + py * wy);
}

__global__ __launch_bounds__(256) void hist_kernel(
    const int* __restrict__ ei, int* __restrict__ deg, int E)
{
    int base = (blockIdx.x * 256 + threadIdx.x) * 4;
    const int* dsts = ei + E;
    if (base + 3 < E) {
        int4 d = *(const int4*)(dsts + base);
        atomicAdd(deg + d.x, 1); atomicAdd(deg + d.y, 1);
        atomicAdd(deg + d.z, 1); atomicAdd(deg + d.w, 1);
    } else {
        for (int i = base; i < E && i < base + 4; ++i) atomicAdd(deg + dsts[i], 1);
    }
}

// Multi-block exclusive scan of deg -> cursor. 1024 items per 256-thread block.
__global__ __launch_bounds__(256) void scan1_kernel(
    const int* __restrict__ deg, int* __restrict__ cursor,
    int* __restrict__ bsum, int N)
{
    __shared__ int wsum[4];
    int tid = threadIdx.x, lane = tid & 63, wv = tid >> 6;
    int base = blockIdx.x * 1024 + tid * 4;
    int v0 = 0, v1 = 0, v2 = 0, v3 = 0;
    if (base + 3 < N) {
        int4 v = *(const int4*)(deg + base);
        v0 = v.x; v1 = v.y; v2 = v.z; v3 = v.w;
    } else if (base < N) {
        v0 = deg[base];
        if (base + 1 < N) v1 = deg[base + 1];
        if (base + 2 < N) v2 = deg[base + 2];
    }
    int s = v0 + v1 + v2 + v3;
    int x = s;
#pragma unroll
    for (int d = 1; d < 64; d <<= 1) {
        int t = __shfl_up(x, d, 64);
        if (lane >= d) x += t;
    }
    if (lane == 63) wsum[wv] = x;
    __syncthreads();
    int add = 0;
#pragma unroll
    for (int w = 0; w < 4; ++w) if (w < wv) add += wsum[w];
    int ex = add + x - s;
    if (base < N) {
        cursor[base] = ex;
        if (base + 1 < N) cursor[base + 1] = ex + v0;
        if (base + 2 < N) cursor[base + 2] = ex + v0 + v1;
        if (base + 3 < N) cursor[base + 3] = ex + v0 + v1 + v2;
    }
    if (tid == 255) bsum[blockIdx.x] = add + x;
}

__global__ __launch_bounds__(64) void scan2_kernel(int* __restrict__ bsum, int nb)
{
    int lane = threadIdx.x;
    int total = 0;
    for (int c0 = 0; c0 < nb; c0 += 64) {
        int i = c0 + lane;
        int v = (i < nb) ? bsum[i] : 0;
        int x = v;
#pragma unroll
        for (int d = 1; d < 64; d <<= 1) {
            int t = __shfl_up(x, d, 64);
            if (lane >= d) x += t;
        }
        if (i < nb) bsum[i] = total + x - v;
        total += __shfl(x, 63, 64);
    }
}

__global__ __launch_bounds__(256) void scan3_kernel(
    int* __restrict__ cursor, const int* __restrict__ bsum, int N)
{
    int base = blockIdx.x * 1024 + threadIdx.x * 4;
    int off = bsum[blockIdx.x];
    if (base + 3 < N) {
        int4 v = *(int4*)(cursor + base);
        v.x += off; v.y += off; v.z += off; v.w += off;
        *(int4*)(cursor + base) = v;
    } else if (base < N) {
        cursor[base] += off;
        if (base + 1 < N) cursor[base + 1] += off;
        if (base + 2 < N) cursor[base + 2] += off;
    }
}

__global__ __launch_bounds__(256) void scatter_kernel(
    const int* __restrict__ ei, int* __restrict__ cursor,
    int2* __restrict__ csr, int E)
{
    int base = (blockIdx.x * 256 + threadIdx.x) * 4;
    if (base >= E) return;
    const int* dsts = ei + E;
    if (base + 3 < E) {
        int4 s = *(const int4*)(ei + base);
        int4 d = *(const int4*)(dsts + base);
        int p0 = atomicAdd(cursor + d.x, 1); csr[p0] = make_int2(s.x, d.x);
        int p1 = atomicAdd(cursor + d.y, 1); csr[p1] = make_int2(s.y, d.y);
        int p2 = atomicAdd(cursor + d.z, 1); csr[p2] = make_int2(s.z, d.z);
        int p3 = atomicAdd(cursor + d.w, 1); csr[p3] = make_int2(s.w, d.w);
    } else {
        for (int i = base; i < E && i < base + 4; ++i) {
            int d = dsts[i];
            int p = atomicAdd(cursor + d, 1);
            csr[p] = make_int2(ei[i], d);
        }
    }
}

__device__ __forceinline__ void flush_seg(
    unsigned int* __restrict__ hout, const float* __restrict__ bias,
    int dst, int c0, const float* macc)
{
    unsigned int* row = hout + (size_t)dst * 32 + c0;
#pragma unroll
    for (int j = 0; j < 16; ++j) {
        float x = macc[j] + bias[c0 + j];
        if (x > 0.0f) atomicMax(row + j, __float_as_uint(x));
    }
}

// Edge-centric layer: 8 consecutive CSR edges per thread, 16-channel halves.
// Per-thread serial max in regs (bias folded at flush); mid-thread dst change
// flushes directly (rare). Tail segments combined by one in-wave segmented
// shfl-max; only run-head lanes issue global atomicMax.
__global__ __launch_bounds__(256) void edge_layer_kernel(
    const int2* __restrict__ csr, const float* __restrict__ A,
    const float* __restrict__ B, const float* __restrict__ w,
    const float* __restrict__ bias, unsigned int* __restrict__ hout, int E)
{
    int tid = threadIdx.x;
    int lane = tid & 63;
    int c0 = (tid >> 7) * 16;                 // wave-uniform channel half
    int base = blockIdx.x * 1024 + (tid & 127) * 8;

    float macc[16];
#pragma unroll
    for (int j = 0; j < 16; ++j) macc[j] = NEG_BIG;
    int cur = -1;

#pragma unroll 1
    for (int i = 0; i < 8; ++i) {
        int e = base + i;
        if (e >= E) break;
        int2 sd = csr[e];
        if (sd.y != cur) {
            if (cur >= 0) flush_seg(hout, bias, cur, c0, macc);
            cur = sd.y;
#pragma unroll
            for (int j = 0; j < 16; ++j) macc[j] = NEG_BIG;
        }
        const float4* Aq = (const float4*)(A + (size_t)sd.x * 32);
        const float4* Bq = (const float4*)(B + (size_t)sd.y * 32);
        float m[16];
#pragma unroll
        for (int j = 0; j < 16; ++j) m[j] = 0.0f;
#pragma unroll
        for (int q = 0; q < 8; ++q) {
            float4 a = Aq[q];
            float4 b = Bq[q];
            float h0 = fmaxf(a.x + b.x, 0.0f);
            float h1 = fmaxf(a.y + b.y, 0.0f);
            float h2 = fmaxf(a.z + b.z, 0.0f);
            float h3 = fmaxf(a.w + b.w, 0.0f);
            const float* wr = w + (4 * q) * 32 + c0;
#pragma unroll
            for (int j = 0; j < 16; ++j) m[j] = fmaf(h0, wr[j], m[j]);
#pragma unroll
            for (int j = 0; j < 16; ++j) m[j] = fmaf(h1, wr[32 + j], m[j]);
#pragma unroll
            for (int j = 0; j < 16; ++j) m[j] = fmaf(h2, wr[64 + j], m[j]);
#pragma unroll
            for (int j = 0; j < 16; ++j) m[j] = fmaf(h3, wr[96 + j], m[j]);
        }
#pragma unroll
        for (int j = 0; j < 16; ++j) macc[j] = fmaxf(macc[j], m[j]);
    }

    // In-wave segmented max over per-thread tail segments (runs contiguous).
#pragma unroll
    for (int d = 1; d < 64; d <<= 1) {
        int dn = __shfl_down(cur, d, 64);
        bool take = (lane + d < 64) && (dn == cur);
#pragma unroll
        for (int j = 0; j < 16; ++j) {
            float t = __shfl_down(macc[j], d, 64);
            if (take) macc[j] = fmaxf(macc[j], t);
        }
    }
    int dp = __shfl_up(cur, 1, 64);
    bool head = (cur >= 0) && (lane == 0 || dp != cur);
    if (head) flush_seg(hout, bias, cur, c0, macc);
}

// batch is sorted: one block per graph, binary-search the node range.
__global__ __launch_bounds__(256) void pool_kernel(
    const float* __restrict__ h2, const int* __restrict__ batch,
    float* __restrict__ gbuf, int N)
{
    int g = blockIdx.x;
    __shared__ int sbound[2];
    __shared__ float red[256];
    if (threadIdx.x < 2) {
        int target = g + (int)threadIdx.x;
        int lo = 0, hi = N;
        while (lo < hi) {
            int mid = (lo + hi) >> 1;
            if (batch[mid] < target) lo = mid + 1; else hi = mid;
        }
        sbound[threadIdx.x] = lo;
    }
    __syncthreads();
    int start = sbound[0], end = sbound[1];
    int c = threadIdx.x & 31, r = threadIdx.x >> 5;
    float mx = 0.0f;
    for (int n = start + r; n < end; n += 8)
        mx = fmaxf(mx, h2[(size_t)n * 32 + c]);
    red[threadIdx.x] = mx;
    __syncthreads();
    if (r < 4) red[threadIdx.x] = fmaxf(red[threadIdx.x], red[threadIdx.x + 128]);
    __syncthreads();
    if (r < 2) red[threadIdx.x] = fmaxf(red[threadIdx.x], red[threadIdx.x + 64]);
    __syncthreads();
    if (r == 0) gbuf[g * 32 + c] = fmaxf(red[threadIdx.x], red[threadIdx.x + 32]);
}

__global__ __launch_bounds__(192) void out_kernel(
    const float* __restrict__ gbuf, const float* __restrict__ wc,
    const float* __restrict__ bc, float* __restrict__ out, int G)
{
    int t = threadIdx.x;
    if (t >= G * 3) return;
    int g = t / 3, j = t % 3;
    float s = bc[j];
#pragma unroll
    for (int c = 0; c < 32; ++c)
        s = fmaf(gbuf[g * 32 + c], wc[c * 3 + j], s);
    out[t] = s;
}

extern "C" void kernel_launch(void* const* d_in, const int* in_sizes, int n_in,
                              void* d_out, int out_size, void* d_ws, size_t ws_size,
                              hipStream_t stream) {
    const float* pos = (const float*)d_in[0];
    const float* w1a = (const float*)d_in[1];
    const float* b1a = (const float*)d_in[2];
    const float* w1b = (const float*)d_in[3];
    const float* b1b = (const float*)d_in[4];
    const float* w2a = (const float*)d_in[5];
    const float* b2a = (const float*)d_in[6];
    const float* w2b = (const float*)d_in[7];
    const float* b2b = (const float*)d_in[8];
    const float* wc  = (const float*)d_in[9];
    const float* bc  = (const float*)d_in[10];
    const int* ei    = (const int*)d_in[11];
    const int* batch = (const int*)d_in[12];

    const int N = in_sizes[12];
    const int E = in_sizes[11] / 2;
    const int G = out_size / 3;
    const size_t NC = (size_t)N * 32;

    int* deg     = (int*)d_ws;
    int* cursor  = deg + N;
    int2* csr    = (int2*)(cursor + N);
    int* bsum    = (int*)(csr + E);
    float* A     = (float*)(bsum + 4096);
    float* B     = A + NC;
    float* h     = B + NC;               // shared by layer1 and layer2
    float* gbuf  = h + NC;

    int ncBlocks = ((int)NC + 255) / 256;
    int sBlocks  = (N + 1023) / 1024;
    int e4Blocks = (E + 1023) / 1024;
    int edBlocks = (E + 1023) / 1024;    // 1024 edges per block

    hipMemsetAsync(deg, 0, (size_t)N * sizeof(int), stream);
    hipMemsetAsync(h, 0, NC * sizeof(float), stream);

    hist_kernel<<<e4Blocks, 256, 0, stream>>>(ei, deg, E);
    scan1_kernel<<<sBlocks, 256, 0, stream>>>(deg, cursor, bsum, N);
    scan2_kernel<<<1, 64, 0, stream>>>(bsum, sBlocks);
    scan3_kernel<<<sBlocks, 256, 0, stream>>>(cursor, bsum, N);
    scatter_kernel<<<e4Blocks, 256, 0, stream>>>(ei, cursor, csr, E);

    pre1_kernel<<<ncBlocks, 256, 0, stream>>>(pos, w1a, b1a, A, B, N);
    edge_layer_kernel<<<edBlocks, 256, 0, stream>>>(csr, A, B, w1b, b1b,
                                                    (unsigned int*)h, E);
    pre2_kernel<<<ncBlocks, 256, 0, stream>>>(pos, h, w2a, b2a, A, B, N);
    hipMemsetAsync(h, 0, NC * sizeof(float), stream);
    edge_layer_kernel<<<edBlocks, 256, 0, stream>>>(csr, A, B, w2b, b2b,
                                                    (unsigned int*)h, E);
    pool_kernel<<<G, 256, 0, stream>>>(h, batch, gbuf, N);
    out_kernel<<<1, 192, 0, stream>>>(gbuf, wc, bc, (float*)d_out, G);
}

// Round 6
// 1543.177 us; speedup vs baseline: 1.2859x; 1.2859x over previous
//
#include <hip/hip_runtime.h>
#include <hip/hip_bf16.h>

// Workspace layout (4B units):
// [deg:N][cursor:N][csr:int2 x E][bsum:4096][A:N*32][B:N*32][h:N*32][gbuf:G*32]
// h/gbuf hold non-negative float bit patterns (global atomicMax on uint).

__global__ __launch_bounds__(256) void pre1_kernel(
    const float* __restrict__ pos, const float* __restrict__ w1a,
    const float* __restrict__ b1a, float* __restrict__ A, float* __restrict__ B, int N)
{
    int t = blockIdx.x * 256 + threadIdx.x;
    if (t >= N * 32) return;
    int n = t >> 5, c = t & 31;
    float px = pos[2 * n], py = pos[2 * n + 1];
    float w0 = w1a[c], w1 = w1a[32 + c], w2 = w1a[64 + c], w3 = w1a[96 + c];
    A[t] = fmaf(px, w0 + w2, fmaf(py, w1 + w3, b1a[c]));
    B[t] = -(px * w2 + py * w3);
}

__global__ __launch_bounds__(256) void pre2_kernel(
    const float* __restrict__ pos, const float* __restrict__ h1,
    const float* __restrict__ w2a, const float* __restrict__ b2a,
    float* __restrict__ A, float* __restrict__ B, int N)
{
    int t = blockIdx.x * 256 + threadIdx.x;
    if (t >= N * 32) return;
    int n = t >> 5, c = t & 31;
    float px = pos[2 * n], py = pos[2 * n + 1];
    float wx = w2a[32 * 32 + c], wy = w2a[33 * 32 + c];
    float s = fmaf(px, wx, fmaf(py, wy, b2a[c]));
    const float* hrow = h1 + (size_t)n * 32;
#pragma unroll
    for (int k = 0; k < 32; ++k) s = fmaf(hrow[k], w2a[k * 32 + c], s);
    A[t] = s;
    B[t] = -(px * wx + py * wy);
}

__global__ __launch_bounds__(256) void hist_kernel(
    const int* __restrict__ ei, int* __restrict__ deg, int E)
{
    int base = (blockIdx.x * 256 + threadIdx.x) * 4;
    const int* dsts = ei + E;
    if (base + 3 < E) {
        int4 d = *(const int4*)(dsts + base);
        atomicAdd(deg + d.x, 1); atomicAdd(deg + d.y, 1);
        atomicAdd(deg + d.z, 1); atomicAdd(deg + d.w, 1);
    } else {
        for (int i = base; i < E && i < base + 4; ++i) atomicAdd(deg + dsts[i], 1);
    }
}

__global__ __launch_bounds__(256) void scan1_kernel(
    const int* __restrict__ deg, int* __restrict__ cursor,
    int* __restrict__ bsum, int N)
{
    __shared__ int wsum[4];
    int tid = threadIdx.x, lane = tid & 63, wv = tid >> 6;
    int base = blockIdx.x * 1024 + tid * 4;
    int v0 = 0, v1 = 0, v2 = 0, v3 = 0;
    if (base + 3 < N) {
        int4 v = *(const int4*)(deg + base);
        v0 = v.x; v1 = v.y; v2 = v.z; v3 = v.w;
    } else if (base < N) {
        v0 = deg[base];
        if (base + 1 < N) v1 = deg[base + 1];
        if (base + 2 < N) v2 = deg[base + 2];
    }
    int s = v0 + v1 + v2 + v3;
    int x = s;
#pragma unroll
    for (int d = 1; d < 64; d <<= 1) {
        int t = __shfl_up(x, d, 64);
        if (lane >= d) x += t;
    }
    if (lane == 63) wsum[wv] = x;
    __syncthreads();
    int add = 0;
#pragma unroll
    for (int w = 0; w < 4; ++w) if (w < wv) add += wsum[w];
    int ex = add + x - s;
    if (base < N) {
        cursor[base] = ex;
        if (base + 1 < N) cursor[base + 1] = ex + v0;
        if (base + 2 < N) cursor[base + 2] = ex + v0 + v1;
        if (base + 3 < N) cursor[base + 3] = ex + v0 + v1 + v2;
    }
    if (tid == 255) bsum[blockIdx.x] = add + x;
}

__global__ __launch_bounds__(64) void scan2_kernel(int* __restrict__ bsum, int nb)
{
    int lane = threadIdx.x;
    int total = 0;
    for (int c0 = 0; c0 < nb; c0 += 64) {
        int i = c0 + lane;
        int v = (i < nb) ? bsum[i] : 0;
        int x = v;
#pragma unroll
        for (int d = 1; d < 64; d <<= 1) {
            int t = __shfl_up(x, d, 64);
            if (lane >= d) x += t;
        }
        if (i < nb) bsum[i] = total + x - v;
        total += __shfl(x, 63, 64);
    }
}

__global__ __launch_bounds__(256) void scan3_kernel(
    int* __restrict__ cursor, const int* __restrict__ bsum, int N)
{
    int base = blockIdx.x * 1024 + threadIdx.x * 4;
    int off = bsum[blockIdx.x];
    if (base + 3 < N) {
        int4 v = *(int4*)(cursor + base);
        v.x += off; v.y += off; v.z += off; v.w += off;
        *(int4*)(cursor + base) = v;
    } else if (base < N) {
        cursor[base] += off;
        if (base + 1 < N) cursor[base + 1] += off;
        if (base + 2 < N) cursor[base + 2] += off;
    }
}

__global__ __launch_bounds__(256) void scatter_kernel(
    const int* __restrict__ ei, int* __restrict__ cursor,
    int2* __restrict__ csr, int E)
{
    int base = (blockIdx.x * 256 + threadIdx.x) * 4;
    if (base >= E) return;
    const int* dsts = ei + E;
    if (base + 3 < E) {
        int4 s = *(const int4*)(ei + base);
        int4 d = *(const int4*)(dsts + base);
        int p0 = atomicAdd(cursor + d.x, 1); csr[p0] = make_int2(s.x, d.x);
        int p1 = atomicAdd(cursor + d.y, 1); csr[p1] = make_int2(s.y, d.y);
        int p2 = atomicAdd(cursor + d.z, 1); csr[p2] = make_int2(s.z, d.z);
        int p3 = atomicAdd(cursor + d.w, 1); csr[p3] = make_int2(s.w, d.w);
    } else {
        for (int i = base; i < E && i < base + 4; ++i) {
            int d = dsts[i];
            int p = atomicAdd(cursor + d, 1);
            csr[p] = make_int2(ei[i], d);
        }
    }
}

// Edge-centric layer, block = 256 threads = 128 edges x 2 channel-halves.
// Phase 1: all 16 gather loads issued up front (independent -> one vmcnt drain),
//          512 FMAs with wave-uniform weights (s_load), m[16] -> LDS (stride 33,
//          2-way bank alias = free).
// Phase 2: transpose-reduce: thread=(channel,slot) serially maxes each dst-run
//          (pipelined ds_reads, no dependent cross-lane chain), run-heads issue
//          global atomicMax with bias folded at flush.
__global__ __launch_bounds__(256, 4) void edge_layer_kernel(
    const int2* __restrict__ csr, const float* __restrict__ A,
    const float* __restrict__ B, const float* __restrict__ w,
    const float* __restrict__ bias, unsigned int* __restrict__ hout, int E)
{
    __shared__ float sM[128 * 33];
    __shared__ int sdst[128];

    int tid = threadIdx.x;
    int et = tid & 127;                 // edge slot in tile
    int c0 = (tid >> 7) * 16;           // wave-uniform channel half
    int e = blockIdx.x * 128 + et;
    bool valid = e < E;

    int src = 0, dst = -1;
    if (valid) { int2 sd = csr[e]; src = sd.x; dst = sd.y; }
    if (tid < 128) sdst[et] = dst;

    const float4* Aq = (const float4*)(A + (size_t)src * 32);
    const float4* Bq = (const float4*)(B + (size_t)dst * 32);
    float4 av[8], bv[8];
#pragma unroll
    for (int q = 0; q < 8; ++q) av[q] = valid ? Aq[q] : make_float4(0, 0, 0, 0);
#pragma unroll
    for (int q = 0; q < 8; ++q) bv[q] = valid ? Bq[q] : make_float4(0, 0, 0, 0);

    float m[16];
#pragma unroll
    for (int j = 0; j < 16; ++j) m[j] = 0.0f;

#pragma unroll
    for (int q = 0; q < 8; ++q) {
        float h0 = fmaxf(av[q].x + bv[q].x, 0.0f);
        float h1 = fmaxf(av[q].y + bv[q].y, 0.0f);
        float h2 = fmaxf(av[q].z + bv[q].z, 0.0f);
        float h3 = fmaxf(av[q].w + bv[q].w, 0.0f);
        const float* wr = w + (4 * q) * 32 + c0;   // wave-uniform -> s_load
#pragma unroll
        for (int j = 0; j < 16; ++j) m[j] = fmaf(h0, wr[j], m[j]);
#pragma unroll
        for (int j = 0; j < 16; ++j) m[j] = fmaf(h1, wr[32 + j], m[j]);
#pragma unroll
        for (int j = 0; j < 16; ++j) m[j] = fmaf(h2, wr[64 + j], m[j]);
#pragma unroll
        for (int j = 0; j < 16; ++j) m[j] = fmaf(h3, wr[96 + j], m[j]);
    }

    float* mrow = sM + et * 33 + c0;
#pragma unroll
    for (int j = 0; j < 16; ++j) mrow[j] = m[j];
    __syncthreads();

    // transpose-reduce: c = tid&31, slots strided by 8
    int c = tid & 31;
    float bc_ = bias[c];
    for (int s = tid >> 5; s < 128; s += 8) {
        int d = sdst[s];
        if (d < 0) break;                          // tail-only invalids
        if (s > 0 && sdst[s - 1] == d) continue;   // not a run head
        float v = sM[s * 33 + c];
        int j = s + 1;
        while (j < 128 && sdst[j] == d) { v = fmaxf(v, sM[j * 33 + c]); ++j; }
        float x = v + bc_;
        if (x > 0.0f) atomicMax(hout + (size_t)d * 32 + c, __float_as_uint(x));
    }
}

// Pool: 16 blocks per graph, sorted batch -> binary-search range, atomicMax to gbuf.
__global__ __launch_bounds__(256) void pool_kernel(
    const float* __restrict__ h2, const int* __restrict__ batch,
    unsigned int* __restrict__ gbuf, int N)
{
    int g = blockIdx.x, p = blockIdx.y;
    __shared__ int sbound[2];
    __shared__ float red[256];
    if (threadIdx.x < 2) {
        int target = g + (int)threadIdx.x;
        int lo = 0, hi = N;
        while (lo < hi) {
            int mid = (lo + hi) >> 1;
            if (batch[mid] < target) lo = mid + 1; else hi = mid;
        }
        sbound[threadIdx.x] = lo;
    }
    __syncthreads();
    int start = sbound[0], end = sbound[1];
    int c = threadIdx.x & 31, r = threadIdx.x >> 5;
    float mx = 0.0f;
    for (int n = start + p * 8 + r; n < end; n += 128)
        mx = fmaxf(mx, h2[(size_t)n * 32 + c]);
    red[threadIdx.x] = mx;
    __syncthreads();
    if (r < 4) red[threadIdx.x] = fmaxf(red[threadIdx.x], red[threadIdx.x + 128]);
    __syncthreads();
    if (r < 2) red[threadIdx.x] = fmaxf(red[threadIdx.x], red[threadIdx.x + 64]);
    __syncthreads();
    if (r == 0) {
        float v = fmaxf(red[threadIdx.x], red[threadIdx.x + 32]);
        if (v > 0.0f) atomicMax(gbuf + g * 32 + c, __float_as_uint(v));
    }
}

__global__ __launch_bounds__(192) void out_kernel(
    const float* __restrict__ gbuf, const float* __restrict__ wc,
    const float* __restrict__ bc, float* __restrict__ out, int G)
{
    int t = threadIdx.x;
    if (t >= G * 3) return;
    int g = t / 3, j = t % 3;
    float s = bc[j];
#pragma unroll
    for (int c = 0; c < 32; ++c)
        s = fmaf(gbuf[g * 32 + c], wc[c * 3 + j], s);
    out[t] = s;
}

extern "C" void kernel_launch(void* const* d_in, const int* in_sizes, int n_in,
                              void* d_out, int out_size, void* d_ws, size_t ws_size,
                              hipStream_t stream) {
    const float* pos = (const float*)d_in[0];
    const float* w1a = (const float*)d_in[1];
    const float* b1a = (const float*)d_in[2];
    const float* w1b = (const float*)d_in[3];
    const float* b1b = (const float*)d_in[4];
    const float* w2a = (const float*)d_in[5];
    const float* b2a = (const float*)d_in[6];
    const float* w2b = (const float*)d_in[7];
    const float* b2b = (const float*)d_in[8];
    const float* wc  = (const float*)d_in[9];
    const float* bc  = (const float*)d_in[10];
    const int* ei    = (const int*)d_in[11];
    const int* batch = (const int*)d_in[12];

    const int N = in_sizes[12];
    const int E = in_sizes[11] / 2;
    const int G = out_size / 3;
    const size_t NC = (size_t)N * 32;

    int* deg     = (int*)d_ws;
    int* cursor  = deg + N;
    int2* csr    = (int2*)(cursor + N);
    int* bsum    = (int*)(csr + E);
    float* A     = (float*)(bsum + 4096);
    float* B     = A + NC;
    float* h     = B + NC;               // shared by layer1 and layer2
    float* gbuf  = h + NC;

    int ncBlocks = ((int)NC + 255) / 256;
    int sBlocks  = (N + 1023) / 1024;
    int e4Blocks = (E + 1023) / 1024;
    int edBlocks = (E + 127) / 128;

    hipMemsetAsync(deg, 0, (size_t)N * sizeof(int), stream);
    hipMemsetAsync(h, 0, NC * sizeof(float), stream);
    hipMemsetAsync(gbuf, 0, (size_t)G * 32 * sizeof(float), stream);

    hist_kernel<<<e4Blocks, 256, 0, stream>>>(ei, deg, E);
    scan1_kernel<<<sBlocks, 256, 0, stream>>>(deg, cursor, bsum, N);
    scan2_kernel<<<1, 64, 0, stream>>>(bsum, sBlocks);
    scan3_kernel<<<sBlocks, 256, 0, stream>>>(cursor, bsum, N);
    scatter_kernel<<<e4Blocks, 256, 0, stream>>>(ei, cursor, csr, E);

    pre1_kernel<<<ncBlocks, 256, 0, stream>>>(pos, w1a, b1a, A, B, N);
    edge_layer_kernel<<<edBlocks, 256, 0, stream>>>(csr, A, B, w1b, b1b,
                                                    (unsigned int*)h, E);
    pre2_kernel<<<ncBlocks, 256, 0, stream>>>(pos, h, w2a, b2a, A, B, N);
    hipMemsetAsync(h, 0, NC * sizeof(float), stream);
    edge_layer_kernel<<<edBlocks, 256, 0, stream>>>(csr, A, B, w2b, b2b,
                                                    (unsigned int*)h, E);
    pool_kernel<<<dim3(G, 16), 256, 0, stream>>>(h, batch,
                                                 (unsigned int*)gbuf, N);
    out_kernel<<<1, 192, 0, stream>>>(gbuf, wc, bc, (float*)d_out, G);
}

// Round 7
// 723.426 us; speedup vs baseline: 2.7431x; 2.1332x over previous
//
#include <hip/hip_runtime.h>
#include <hip/hip_bf16.h>

// Workspace layout (4B units):
// [deg:N][cursor:N][csr:int2 x E][bsum:4096][A:N*32][B:N*32][h1:N*32][h2:N*32][gbuf:G*32]
// h1/h2/gbuf hold non-negative float bit patterns (global atomicMax on uint).

#define NEG_BIG (-3.0e38f)

// pre1 also zeroes h1 (saves a memset dispatch; h1 untouched by anyone else here).
__global__ __launch_bounds__(256) void pre1_kernel(
    const float* __restrict__ pos, const float* __restrict__ w1a,
    const float* __restrict__ b1a, float* __restrict__ A, float* __restrict__ B,
    float* __restrict__ h1, int N)
{
    int t = blockIdx.x * 256 + threadIdx.x;
    if (t >= N * 32) return;
    int n = t >> 5, c = t & 31;
    float px = pos[2 * n], py = pos[2 * n + 1];
    float w0 = w1a[c], w1 = w1a[32 + c], w2 = w1a[64 + c], w3 = w1a[96 + c];
    A[t] = fmaf(px, w0 + w2, fmaf(py, w1 + w3, b1a[c]));
    B[t] = -(px * w2 + py * w3);
    h1[t] = 0.0f;
}

// pre2 reads h1, zeroes h2.
__global__ __launch_bounds__(256) void pre2_kernel(
    const float* __restrict__ pos, const float* __restrict__ h1,
    const float* __restrict__ w2a, const float* __restrict__ b2a,
    float* __restrict__ A, float* __restrict__ B, float* __restrict__ h2, int N)
{
    int t = blockIdx.x * 256 + threadIdx.x;
    if (t >= N * 32) return;
    int n = t >> 5, c = t & 31;
    float px = pos[2 * n], py = pos[2 * n + 1];
    float wx = w2a[32 * 32 + c], wy = w2a[33 * 32 + c];
    float s = fmaf(px, wx, fmaf(py, wy, b2a[c]));
    const float* hrow = h1 + (size_t)n * 32;
#pragma unroll
    for (int k = 0; k < 32; ++k) s = fmaf(hrow[k], w2a[k * 32 + c], s);
    A[t] = s;
    B[t] = -(px * wx + py * wy);
    h2[t] = 0.0f;
}

__global__ __launch_bounds__(256) void hist_kernel(
    const int* __restrict__ ei, int* __restrict__ deg, int E)
{
    int base = (blockIdx.x * 256 + threadIdx.x) * 4;
    const int* dsts = ei + E;
    if (base + 3 < E) {
        int4 d = *(const int4*)(dsts + base);
        atomicAdd(deg + d.x, 1); atomicAdd(deg + d.y, 1);
        atomicAdd(deg + d.z, 1); atomicAdd(deg + d.w, 1);
    } else {
        for (int i = base; i < E && i < base + 4; ++i) atomicAdd(deg + dsts[i], 1);
    }
}

__global__ __launch_bounds__(256) void scan1_kernel(
    const int* __restrict__ deg, int* __restrict__ cursor,
    int* __restrict__ bsum, int N)
{
    __shared__ int wsum[4];
    int tid = threadIdx.x, lane = tid & 63, wv = tid >> 6;
    int base = blockIdx.x * 1024 + tid * 4;
    int v0 = 0, v1 = 0, v2 = 0, v3 = 0;
    if (base + 3 < N) {
        int4 v = *(const int4*)(deg + base);
        v0 = v.x; v1 = v.y; v2 = v.z; v3 = v.w;
    } else if (base < N) {
        v0 = deg[base];
        if (base + 1 < N) v1 = deg[base + 1];
        if (base + 2 < N) v2 = deg[base + 2];
    }
    int s = v0 + v1 + v2 + v3;
    int x = s;
#pragma unroll
    for (int d = 1; d < 64; d <<= 1) {
        int t = __shfl_up(x, d, 64);
        if (lane >= d) x += t;
    }
    if (lane == 63) wsum[wv] = x;
    __syncthreads();
    int add = 0;
#pragma unroll
    for (int w = 0; w < 4; ++w) if (w < wv) add += wsum[w];
    int ex = add + x - s;
    if (base < N) {
        cursor[base] = ex;
        if (base + 1 < N) cursor[base + 1] = ex + v0;
        if (base + 2 < N) cursor[base + 2] = ex + v0 + v1;
        if (base + 3 < N) cursor[base + 3] = ex + v0 + v1 + v2;
    }
    if (tid == 255) bsum[blockIdx.x] = add + x;
}

__global__ __launch_bounds__(64) void scan2_kernel(int* __restrict__ bsum, int nb)
{
    int lane = threadIdx.x;
    int total = 0;
    for (int c0 = 0; c0 < nb; c0 += 64) {
        int i = c0 + lane;
        int v = (i < nb) ? bsum[i] : 0;
        int x = v;
#pragma unroll
        for (int d = 1; d < 64; d <<= 1) {
            int t = __shfl_up(x, d, 64);
            if (lane >= d) x += t;
        }
        if (i < nb) bsum[i] = total + x - v;
        total += __shfl(x, 63, 64);
    }
}

__global__ __launch_bounds__(256) void scan3_kernel(
    int* __restrict__ cursor, const int* __restrict__ bsum, int N)
{
    int base = blockIdx.x * 1024 + threadIdx.x * 4;
    int off = bsum[blockIdx.x];
    if (base + 3 < N) {
        int4 v = *(int4*)(cursor + base);
        v.x += off; v.y += off; v.z += off; v.w += off;
        *(int4*)(cursor + base) = v;
    } else if (base < N) {
        cursor[base] += off;
        if (base + 1 < N) cursor[base + 1] += off;
        if (base + 2 < N) cursor[base + 2] += off;
    }
}

__global__ __launch_bounds__(256) void scatter_kernel(
    const int* __restrict__ ei, int* __restrict__ cursor,
    int2* __restrict__ csr, int E)
{
    int base = (blockIdx.x * 256 + threadIdx.x) * 4;
    if (base >= E) return;
    const int* dsts = ei + E;
    if (base + 3 < E) {
        int4 s = *(const int4*)(ei + base);
        int4 d = *(const int4*)(dsts + base);
        int p0 = atomicAdd(cursor + d.x, 1); csr[p0] = make_int2(s.x, d.x);
        int p1 = atomicAdd(cursor + d.y, 1); csr[p1] = make_int2(s.y, d.y);
        int p2 = atomicAdd(cursor + d.z, 1); csr[p2] = make_int2(s.z, d.z);
        int p3 = atomicAdd(cursor + d.w, 1); csr[p3] = make_int2(s.w, d.w);
    } else {
        for (int i = base; i < E && i < base + 4; ++i) {
            int d = dsts[i];
            int p = atomicAdd(cursor + d, 1);
            csr[p] = make_int2(ei[i], d);
        }
    }
}

// Edge-centric layer: block = 256 threads = 256 edges, one FULL output row per
// thread (32 channels). Phase 1: prefetch A/B rows (16 independent float4
// loads), 1024 FMAs (weights wave-uniform -> s_load), write m[32] to LDS with
// stride 36 (16B-aligned, <=2-way bank alias = free).
// Phase 2: thread (c,g) scans fixed slot chunk [32g,32g+32) -- all LDS
// addresses affine in the loop index => fully pipelined ds_reads, no dependent
// chain. Flush on dst change (runs avg ~32 -> ~2 filtered atomics/thread).
__global__ __launch_bounds__(256, 4) void edge_layer_kernel(
    const int2* __restrict__ csr, const float* __restrict__ A,
    const float* __restrict__ B, const float* __restrict__ w,
    const float* __restrict__ bias, unsigned int* __restrict__ hout, int E)
{
    __shared__ float sM[256 * 36];
    __shared__ int sdst[256];

    int tid = threadIdx.x;
    int e = blockIdx.x * 256 + tid;
    bool valid = e < E;

    int src = 0, dst = -1;
    if (valid) { int2 sd = csr[e]; src = sd.x; dst = sd.y; }
    sdst[tid] = dst;
    int gidx = valid ? dst : 0;

    const float4* Aq = (const float4*)(A + (size_t)src * 32);
    const float4* Bq = (const float4*)(B + (size_t)gidx * 32);
    float4 av[8], bv[8];
#pragma unroll
    for (int q = 0; q < 8; ++q) av[q] = Aq[q];
#pragma unroll
    for (int q = 0; q < 8; ++q) bv[q] = Bq[q];

    float m[32];
#pragma unroll
    for (int j = 0; j < 32; ++j) m[j] = 0.0f;

#pragma unroll
    for (int q = 0; q < 8; ++q) {
        float h0 = fmaxf(av[q].x + bv[q].x, 0.0f);
        float h1 = fmaxf(av[q].y + bv[q].y, 0.0f);
        float h2 = fmaxf(av[q].z + bv[q].z, 0.0f);
        float h3 = fmaxf(av[q].w + bv[q].w, 0.0f);
        const float* wr = w + (4 * q) * 32;        // wave-uniform -> s_load
#pragma unroll
        for (int j = 0; j < 32; ++j) m[j] = fmaf(h0, wr[j], m[j]);
#pragma unroll
        for (int j = 0; j < 32; ++j) m[j] = fmaf(h1, wr[32 + j], m[j]);
#pragma unroll
        for (int j = 0; j < 32; ++j) m[j] = fmaf(h2, wr[64 + j], m[j]);
#pragma unroll
        for (int j = 0; j < 32; ++j) m[j] = fmaf(h3, wr[96 + j], m[j]);
    }

    float* mrow = sM + tid * 36;
#pragma unroll
    for (int q = 0; q < 8; ++q)
        *(float4*)(mrow + 4 * q) = make_float4(m[4 * q], m[4 * q + 1],
                                               m[4 * q + 2], m[4 * q + 3]);
    __syncthreads();

    // Phase 2: strided chunk scan, statically addressed.
    int c = tid & 31;
    int g = tid >> 5;
    int s0 = g * 32;
    float bc_ = bias[c];
    float run = NEG_BIG;
    int cur = -2;   // sentinel != any dst, != -1
#pragma unroll 8
    for (int i = 0; i < 32; ++i) {
        int s = s0 + i;
        int d = sdst[s];
        float v = sM[s * 36 + c];
        if (d != cur) {
            if (cur >= 0) {
                float x = run + bc_;
                if (x > 0.0f)
                    atomicMax(hout + (size_t)cur * 32 + c, __float_as_uint(x));
            }
            cur = d;
            run = v;
        } else {
            run = fmaxf(run, v);
        }
    }
    if (cur >= 0) {
        float x = run + bc_;
        if (x > 0.0f) atomicMax(hout + (size_t)cur * 32 + c, __float_as_uint(x));
    }
}

// Pool: 16 blocks per graph, sorted batch -> binary-search range, atomicMax to gbuf.
__global__ __launch_bounds__(256) void pool_kernel(
    const float* __restrict__ h2, const int* __restrict__ batch,
    unsigned int* __restrict__ gbuf, int N)
{
    int g = blockIdx.x, p = blockIdx.y;
    __shared__ int sbound[2];
    __shared__ float red[256];
    if (threadIdx.x < 2) {
        int target = g + (int)threadIdx.x;
        int lo = 0, hi = N;
        while (lo < hi) {
            int mid = (lo + hi) >> 1;
            if (batch[mid] < target) lo = mid + 1; else hi = mid;
        }
        sbound[threadIdx.x] = lo;
    }
    __syncthreads();
    int start = sbound[0], end = sbound[1];
    int c = threadIdx.x & 31, r = threadIdx.x >> 5;
    float mx = 0.0f;
    for (int n = start + p * 8 + r; n < end; n += 128)
        mx = fmaxf(mx, h2[(size_t)n * 32 + c]);
    red[threadIdx.x] = mx;
    __syncthreads();
    if (r < 4) red[threadIdx.x] = fmaxf(red[threadIdx.x], red[threadIdx.x + 128]);
    __syncthreads();
    if (r < 2) red[threadIdx.x] = fmaxf(red[threadIdx.x], red[threadIdx.x + 64]);
    __syncthreads();
    if (r == 0) {
        float v = fmaxf(red[threadIdx.x], red[threadIdx.x + 32]);
        if (v > 0.0f) atomicMax(gbuf + g * 32 + c, __float_as_uint(v));
    }
}

__global__ __launch_bounds__(192) void out_kernel(
    const float* __restrict__ gbuf, const float* __restrict__ wc,
    const float* __restrict__ bc, float* __restrict__ out, int G)
{
    int t = threadIdx.x;
    if (t >= G * 3) return;
    int g = t / 3, j = t % 3;
    float s = bc[j];
#pragma unroll
    for (int c = 0; c < 32; ++c)
        s = fmaf(gbuf[g * 32 + c], wc[c * 3 + j], s);
    out[t] = s;
}

extern "C" void kernel_launch(void* const* d_in, const int* in_sizes, int n_in,
                              void* d_out, int out_size, void* d_ws, size_t ws_size,
                              hipStream_t stream) {
    const float* pos = (const float*)d_in[0];
    const float* w1a = (const float*)d_in[1];
    const float* b1a = (const float*)d_in[2];
    const float* w1b = (const float*)d_in[3];
    const float* b1b = (const float*)d_in[4];
    const float* w2a = (const float*)d_in[5];
    const float* b2a = (const float*)d_in[6];
    const float* w2b = (const float*)d_in[7];
    const float* b2b = (const float*)d_in[8];
    const float* wc  = (const float*)d_in[9];
    const float* bc  = (const float*)d_in[10];
    const int* ei    = (const int*)d_in[11];
    const int* batch = (const int*)d_in[12];

    const int N = in_sizes[12];
    const int E = in_sizes[11] / 2;
    const int G = out_size / 3;
    const size_t NC = (size_t)N * 32;

    int* deg     = (int*)d_ws;
    int* cursor  = deg + N;
    int2* csr    = (int2*)(cursor + N);
    int* bsum    = (int*)(csr + E);
    float* A     = (float*)(bsum + 4096);
    float* B     = A + NC;
    float* h1    = B + NC;
    float* h2    = h1 + NC;
    float* gbuf  = h2 + NC;

    int ncBlocks = ((int)NC + 255) / 256;
    int sBlocks  = (N + 1023) / 1024;
    int e4Blocks = (E + 1023) / 1024;
    int edBlocks = (E + 255) / 256;

    hipMemsetAsync(deg, 0, (size_t)N * sizeof(int), stream);
    hipMemsetAsync(gbuf, 0, (size_t)G * 32 * sizeof(float), stream);

    hist_kernel<<<e4Blocks, 256, 0, stream>>>(ei, deg, E);
    scan1_kernel<<<sBlocks, 256, 0, stream>>>(deg, cursor, bsum, N);
    scan2_kernel<<<1, 64, 0, stream>>>(bsum, sBlocks);
    scan3_kernel<<<sBlocks, 256, 0, stream>>>(cursor, bsum, N);
    scatter_kernel<<<e4Blocks, 256, 0, stream>>>(ei, cursor, csr, E);

    pre1_kernel<<<ncBlocks, 256, 0, stream>>>(pos, w1a, b1a, A, B, h1, N);
    edge_layer_kernel<<<edBlocks, 256, 0, stream>>>(csr, A, B, w1b, b1b,
                                                    (unsigned int*)h1, E);
    pre2_kernel<<<ncBlocks, 256, 0, stream>>>(pos, h1, w2a, b2a, A, B, h2, N);
    edge_layer_kernel<<<edBlocks, 256, 0, stream>>>(csr, A, B, w2b, b2b,
                                                    (unsigned int*)h2, E);
    pool_kernel<<<dim3(G, 16), 256, 0, stream>>>(h2, batch,
                                                 (unsigned int*)gbuf, N);
    out_kernel<<<1, 192, 0, stream>>>(gbuf, wc, bc, (float*)d_out, G);
}